// Round 2
// baseline (275.243 us; speedup 1.0000x reference)
//
#include <hip/hip_runtime.h>

typedef _Float16 f16;
typedef _Float16 f16x4 __attribute__((ext_vector_type(4)));
typedef _Float16 f16x8 __attribute__((ext_vector_type(8)));
typedef float    f32x4 __attribute__((ext_vector_type(4)));

#define QK_SCALE 11.5416528f  // 8 * log2(e): scores pre-scaled into exp2 domain

__device__ __forceinline__ void g2l16(const void* g, void* l) {
  __builtin_amdgcn_global_load_lds(
      (__attribute__((address_space(1))) const unsigned int*)g,
      (__attribute__((address_space(3))) unsigned int*)l, 16, 0, 0);
}

__device__ __forceinline__ f32x4 mfma16(f16x8 a, f16x8 b, f32x4 c) {
  return __builtin_amdgcn_mfma_f32_16x16x32_f16(a, b, c, 0, 0, 0);
}

// XOR-swizzled LDS offsets (f16 units). Rows of 64 f16 (8x16B chunks) / 32 f16 (4x16B chunks).
__device__ __forceinline__ int swz64(int row, int c) { return row * 64 + ((c ^ (row & 7)) << 3); }
__device__ __forceinline__ int swz32(int row, int c) { return row * 32 + ((c ^ ((row >> 1) & 3)) << 3); }

// ---------------- fp32 -> fp16 hi/lo split (vectorized) ----------------
__global__ __launch_bounds__(256) void k_split(const float* __restrict__ in,
                                               f16* __restrict__ hi, f16* __restrict__ lo, int n4) {
  int i = blockIdx.x * 256 + threadIdx.x;
  if (i >= n4) return;
  f32x4 v = ((const f32x4*)in)[i];
  f16x4 h, l;
#pragma unroll
  for (int j = 0; j < 4; ++j) {
    f16 hv = (f16)v[j];
    h[j] = hv;
    l[j] = (f16)(v[j] - (float)hv);
  }
  ((f16x4*)hi)[i] = h;
  ((f16x4*)lo)[i] = l;
}

// ---------------- transpose fp32 [K][N] -> fp16 [N][K] (hi, optional lo) ----------------
template <bool WLO>
__global__ __launch_bounds__(256) void k_transpose_split(const float* __restrict__ in, int K, int N,
                                                         f16* __restrict__ oh, f16* __restrict__ ol) {
  __shared__ float t[32][33];
  const int tx = threadIdx.x, ty = threadIdx.y;
  const int n0 = blockIdx.x * 32, k0 = blockIdx.y * 32;
#pragma unroll
  for (int j = 0; j < 4; ++j)
    t[ty + j * 8][tx] = in[(size_t)(k0 + ty + j * 8) * N + n0 + tx];
  __syncthreads();
#pragma unroll
  for (int j = 0; j < 4; ++j) {
    float v = t[tx][ty + j * 8];
    f16 hv = (f16)v;
    size_t o = (size_t)(n0 + ty + j * 8) * K + k0 + tx;
    oh[o] = hv;
    if (WLO) ol[o] = (f16)(v - (float)hv);
  }
}

// ---------------- GEMM: C[M,N] = A[M,K] * B[K,N], B given transposed [N][K] ----------------
// EPI 0: qkv scatter (bias, split q(scaled)/k hi+lo per-head, vT fp16)
// EPI 1: relu -> fp16 out
// EPI 2: bias -> fp32 out
template <int EPI, bool SPLIT>
__global__ __launch_bounds__(256, 2) void k_gemm(
    const f16* __restrict__ Ah, const f16* __restrict__ Al,
    const f16* __restrict__ Bh, const f16* __restrict__ Bl,
    const float* __restrict__ bias,
    float* __restrict__ outF, f16* __restrict__ outH,
    f16* __restrict__ oqh, f16* __restrict__ oql,
    f16* __restrict__ okh, f16* __restrict__ okl, f16* __restrict__ ovT,
    int M, int N, int K) {
  constexpr int NB = SPLIT ? 2 : 1;
  __shared__ f16 As[NB][128 * 32];
  __shared__ f16 Bs[NB][128 * 32];

  const int tid = threadIdx.x;
  const int bm = blockIdx.x, bn = blockIdx.y;
  const int w = tid >> 6, lane = tid & 63;
  const int wr = w >> 1, wc = w & 1;
  const int lrow = lane & 15, lgrp = lane >> 4;

  f32x4 acc[4][4] = {};

  const int nkt = K >> 5;
  for (int kt = 0; kt < nkt; ++kt) {
    __syncthreads();
    const int kk = kt << 5;
#pragma unroll
    for (int c = 0; c < 2; ++c) {
      const int i = tid + (c << 8);
      const int row = i >> 2;
      const int gch = ((i & 3) ^ ((i >> 3) & 3)) << 3;  // swizzled source chunk
      const size_t aoff = (size_t)(bm * 128 + row) * K + kk + gch;
      const size_t boff = (size_t)(bn * 128 + row) * K + kk + gch;
      g2l16(Ah + aoff, &As[0][i * 8]);
      g2l16(Bh + boff, &Bs[0][i * 8]);
      if (SPLIT) {
        g2l16(Al + aoff, &As[1][i * 8]);
        g2l16(Bl + boff, &Bs[1][i * 8]);
      }
    }
    __syncthreads();

    f16x8 a0[4], a1[4], b0[4], b1[4];
#pragma unroll
    for (int mf = 0; mf < 4; ++mf) {
      const int off = swz32(wr * 64 + mf * 16 + lrow, lgrp);
      a0[mf] = *(const f16x8*)&As[0][off];
      if (SPLIT) a1[mf] = *(const f16x8*)&As[SPLIT ? 1 : 0][off];
    }
#pragma unroll
    for (int nf = 0; nf < 4; ++nf) {
      const int off = swz32(wc * 64 + nf * 16 + lrow, lgrp);
      b0[nf] = *(const f16x8*)&Bs[0][off];
      if (SPLIT) b1[nf] = *(const f16x8*)&Bs[SPLIT ? 1 : 0][off];
    }
#pragma unroll
    for (int mf = 0; mf < 4; ++mf)
#pragma unroll
      for (int nf = 0; nf < 4; ++nf) {
        acc[mf][nf] = mfma16(a0[mf], b0[nf], acc[mf][nf]);
        if (SPLIT) {
          acc[mf][nf] = mfma16(a0[mf], b1[nf], acc[mf][nf]);
          acc[mf][nf] = mfma16(a1[mf], b0[nf], acc[mf][nf]);
        }
      }
  }

  const int rowbase = bm * 128 + wr * 64 + lgrp * 4;
  const int colbase = bn * 128 + wc * 64 + lrow;
#pragma unroll
  for (int mf = 0; mf < 4; ++mf) {
#pragma unroll
    for (int nf = 0; nf < 4; ++nf) {
      const int gc = colbase + nf * 16;
      const float bv = bias[gc];
#pragma unroll
      for (int r = 0; r < 4; ++r) {
        const int gr = rowbase + mf * 16 + r;
        const float val = acc[mf][nf][r] + bv;
        if (EPI == 0) {
          const int bb = gr >> 11, tok = gr & 2047;
          const int kind = gc >> 9, hh = (gc >> 6) & 7, dd = gc & 63;
          const size_t bhp = (size_t)((bb << 3) + hh);
          const size_t qidx = (bhp * 2048 + tok) * 64 + dd;
          if (kind == 0) {
            const float sv = val * QK_SCALE;  // fold score scale + log2e into q
            const f16 hv = (f16)sv;
            oqh[qidx] = hv; oql[qidx] = (f16)(sv - (float)hv);
          } else if (kind == 1) {
            const f16 hv = (f16)val;
            okh[qidx] = hv; okl[qidx] = (f16)(val - (float)hv);
          } else {
            ovT[(bhp * 64 + dd) * 2048 + tok] = (f16)val;
          }
        } else if (EPI == 1) {
          outH[(size_t)gr * N + gc] = (f16)fmaxf(val, 0.f);
        } else {
          outF[(size_t)gr * N + gc] = val;
        }
      }
    }
  }
}

// ---------------- fused flash attention ----------------
// grid (16 qtiles, 32 bh); block 256 = 4 waves; wave handles 32 q-rows.
// Q (hi+lo, pre-scaled by 8*log2e) held in registers; K/V staged in LDS (40 KB -> 4 blocks/CU).
// S^T = mfma(K, Q) (split fp16, 3 mfma); online softmax in exp2 domain with defer-max;
// O^T = mfma(V^T, P^T).
__global__ __launch_bounds__(256, 4) void k_attn(
    const f16* __restrict__ Qh, const f16* __restrict__ Ql,
    const f16* __restrict__ Kh, const f16* __restrict__ Kl,
    const f16* __restrict__ Vt, float* __restrict__ out) {
  __shared__ f16 sKh[64 * 64], sKl[64 * 64], sVt[64 * 64];
  __shared__ f16 sPt[4][32 * 64];

  const int tid = threadIdx.x;
  const int qt = blockIdx.x, bh = blockIdx.y;
  const int w = tid >> 6, lane = tid & 63;
  const int lrow = lane & 15, lgrp = lane >> 4;

  // Q fragments straight from global into registers (loop-invariant).
  const size_t qbase = (((size_t)bh * 2048) + qt * 128 + w * 32) * 64;
  f16x8 qh8[2][2], ql8[2][2];
#pragma unroll
  for (int qf = 0; qf < 2; ++qf)
#pragma unroll
    for (int ks = 0; ks < 2; ++ks) {
      const size_t o = qbase + (size_t)(qf * 16 + lrow) * 64 + (ks * 4 + lgrp) * 8;
      qh8[qf][ks] = *(const f16x8*)(Qh + o);
      ql8[qf][ks] = *(const f16x8*)(Ql + o);
    }

  float m_run[2] = {-3e38f, -3e38f};
  float l_run[2] = {0.f, 0.f};
  f32x4 oacc[4][2] = {};

  for (int kt = 0; kt < 32; ++kt) {
    __syncthreads();
    {
      const size_t koff = ((size_t)bh * 2048 + (size_t)kt * 64) * 64;
#pragma unroll
      for (int c = 0; c < 2; ++c) {
        const int i = tid + (c << 8);
        const int row = i >> 3;
        const int gch = ((i & 7) ^ (row & 7)) << 3;
        g2l16(Kh + koff + row * 64 + gch, &sKh[i * 8]);
        g2l16(Kl + koff + row * 64 + gch, &sKl[i * 8]);
        g2l16(Vt + ((size_t)bh * 64 + row) * 2048 + (size_t)kt * 64 + gch, &sVt[i * 8]);
      }
    }
    __syncthreads();

    f32x4 sacc[4][2] = {};
#pragma unroll
    for (int ks = 0; ks < 2; ++ks) {
#pragma unroll
      for (int kf = 0; kf < 4; ++kf) {
        const int off = swz64(kf * 16 + lrow, ks * 4 + lgrp);
        const f16x8 kh8 = *(const f16x8*)&sKh[off];
        const f16x8 kl8 = *(const f16x8*)&sKl[off];
#pragma unroll
        for (int qf = 0; qf < 2; ++qf) {
          sacc[kf][qf] = mfma16(kh8, qh8[qf][ks], sacc[kf][qf]);
          sacc[kf][qf] = mfma16(kh8, ql8[qf][ks], sacc[kf][qf]);
          sacc[kf][qf] = mfma16(kl8, qh8[qf][ks], sacc[kf][qf]);
        }
      }
    }

#pragma unroll
    for (int qf = 0; qf < 2; ++qf) {
      float mt = sacc[0][qf][0];
#pragma unroll
      for (int kf = 0; kf < 4; ++kf)
#pragma unroll
        for (int r = 0; r < 4; ++r) mt = fmaxf(mt, sacc[kf][qf][r]);
      mt = fmaxf(mt, __shfl_xor(mt, 16, 64));
      mt = fmaxf(mt, __shfl_xor(mt, 32, 64));
      float mcur = m_run[qf];
      // defer-max: only rescale when some row's tile max grew past m+8 (P bounded by 2^8)
      if (!__all(mt <= mcur + 8.0f)) {
        const float mnew = fmaxf(mcur, mt);
        const float corr = __builtin_amdgcn_exp2f(mcur - mnew);
        m_run[qf] = mnew;
        l_run[qf] *= corr;
#pragma unroll
        for (int hf = 0; hf < 4; ++hf) oacc[hf][qf] = oacc[hf][qf] * corr;
        mcur = mnew;
      }
      float ps = 0.f;
      const int qrow = qf * 16 + lrow;
#pragma unroll
      for (int kf = 0; kf < 4; ++kf) {
        f16x4 pv;
#pragma unroll
        for (int r = 0; r < 4; ++r) {
          const float p = __builtin_amdgcn_exp2f(sacc[kf][qf][r] - mcur);
          ps += p;
          pv[r] = (f16)p;
        }
        *(f16x4*)&sPt[w][swz64(qrow, kf * 2 + (lgrp >> 1)) + ((lgrp & 1) << 2)] = pv;
      }
      ps += __shfl_xor(ps, 16, 64);
      ps += __shfl_xor(ps, 32, 64);
      l_run[qf] += ps;
    }

#pragma unroll
    for (int ks = 0; ks < 2; ++ks) {
      f16x8 pb0 = *(const f16x8*)&sPt[w][swz64(0 * 16 + lrow, ks * 4 + lgrp)];
      f16x8 pb1 = *(const f16x8*)&sPt[w][swz64(1 * 16 + lrow, ks * 4 + lgrp)];
#pragma unroll
      for (int hf = 0; hf < 4; ++hf) {
        const f16x8 va = *(const f16x8*)&sVt[swz64(hf * 16 + lrow, ks * 4 + lgrp)];
        oacc[hf][0] = mfma16(va, pb0, oacc[hf][0]);
        oacc[hf][1] = mfma16(va, pb1, oacc[hf][1]);
      }
    }
  }

  const int b = bh >> 3, h = bh & 7;
#pragma unroll
  for (int qf = 0; qf < 2; ++qf) {
    const float inv = 1.0f / l_run[qf];
    const int t = b * 2048 + qt * 128 + w * 32 + qf * 16 + lrow;
#pragma unroll
    for (int hf = 0; hf < 4; ++hf) {
      f32x4 o = oacc[hf][qf] * inv;
      *(f32x4*)(out + (size_t)t * 512 + h * 64 + hf * 16 + lgrp * 4) = o;
    }
  }
}

// ---------------- residual + layernorm (one wave per row of 512) ----------------
__global__ __launch_bounds__(64) void k_ln(const float* __restrict__ X, const float* __restrict__ R,
                                           const float* __restrict__ g, const float* __restrict__ be,
                                           float* __restrict__ outF, f16* __restrict__ outH) {
  const int row = blockIdx.x, t = threadIdx.x;
  const size_t base = (size_t)row * 512 + t * 8;
  f32x4 x0 = *(const f32x4*)(X + base);
  f32x4 x1 = *(const f32x4*)(X + base + 4);
  f32x4 r0 = *(const f32x4*)(R + base);
  f32x4 r1 = *(const f32x4*)(R + base + 4);
  x0 = x0 + r0;
  x1 = x1 + r1;
  float s = 0.f, ss = 0.f;
#pragma unroll
  for (int j = 0; j < 4; ++j) { s += x0[j] + x1[j]; ss += x0[j] * x0[j] + x1[j] * x1[j]; }
#pragma unroll
  for (int o = 32; o; o >>= 1) {
    s += __shfl_xor(s, o, 64);
    ss += __shfl_xor(ss, o, 64);
  }
  const float mean = s * (1.f / 512.f);
  const float var = ss * (1.f / 512.f) - mean * mean;
  const float rs = rsqrtf(var + 1e-5f);
  f32x4 g0 = *(const f32x4*)(g + t * 8);
  f32x4 g1v = *(const f32x4*)(g + t * 8 + 4);
  f32x4 b0 = *(const f32x4*)(be + t * 8);
  f32x4 b1 = *(const f32x4*)(be + t * 8 + 4);
  f32x4 y0 = (x0 - mean) * rs * g0 + b0;
  f32x4 y1 = (x1 - mean) * rs * g1v + b1;
  *(f32x4*)(outF + base) = y0;
  *(f32x4*)(outF + base + 4) = y1;
  if (outH != nullptr) {
    f16x8 hx;
#pragma unroll
    for (int j = 0; j < 4; ++j) { hx[j] = (f16)y0[j]; hx[j + 4] = (f16)y1[j]; }
    *(f16x8*)(outH + base) = hx;
  }
}

extern "C" void kernel_launch(void* const* d_in, const int* in_sizes, int n_in,
                              void* d_out, int out_size, void* d_ws, size_t ws_size,
                              hipStream_t stream) {
  (void)in_sizes; (void)n_in; (void)out_size;
  const float* x = (const float*)d_in[0];
  const float* w_qkv = (const float*)d_in[1];
  const float* b_qkv = (const float*)d_in[2];
  const float* w1 = (const float*)d_in[3];
  const float* b1 = (const float*)d_in[4];
  const float* w2 = (const float*)d_in[5];
  const float* b2 = (const float*)d_in[6];
  const float* g1 = (const float*)d_in[7];
  const float* be1 = (const float*)d_in[8];
  const float* g2 = (const float*)d_in[9];
  const float* be2 = (const float*)d_in[10];
  float* out = (float*)d_out;

  char* p = (char*)d_ws;
  auto take = [&](size_t bytes) {
    char* r = p;
    p += (bytes + 255) & ~(size_t)255;
    return r;
  };
  f16* xh = (f16*)take(8192ull * 512 * 2);
  f16* xl = (f16*)take(8192ull * 512 * 2);
  f16* wqkvTh = (f16*)take(1536ull * 512 * 2);
  f16* wqkvTl = (f16*)take(1536ull * 512 * 2);
  f16* w1T = (f16*)take(2048ull * 512 * 2);
  f16* w2T = (f16*)take(512ull * 2048 * 2);
  f16* qh = (f16*)take(32ull * 2048 * 64 * 2);
  f16* ql = (f16*)take(32ull * 2048 * 64 * 2);
  f16* kh = (f16*)take(32ull * 2048 * 64 * 2);
  f16* kl = (f16*)take(32ull * 2048 * 64 * 2);
  f16* vT = (f16*)take(32ull * 64 * 2048 * 2);
  float* attn = (float*)take(8192ull * 512 * 4);
  float* x1f = (float*)take(8192ull * 512 * 4);
  f16* x1h = (f16*)take(8192ull * 512 * 2);
  // reuse regions (stage lifetimes are disjoint):
  f16* hbuf = qh;        // [8192][2048] fp16 = 32MB fits in qh..kl (32MB)
  float* ffb = attn;     // [8192][512] fp32, attn consumed by LN1 before ff2

  if ((size_t)(p - (char*)d_ws) > ws_size) return;  // insufficient workspace -> loud validation fail

  dim3 tb(32, 8);
  k_split<<<4096, 256, 0, stream>>>(x, xh, xl, 8192 * 512 / 4);
  k_transpose_split<true><<<dim3(1536 / 32, 512 / 32), tb, 0, stream>>>(w_qkv, 512, 1536, wqkvTh, wqkvTl);
  k_transpose_split<false><<<dim3(2048 / 32, 512 / 32), tb, 0, stream>>>(w1, 512, 2048, w1T, nullptr);
  k_transpose_split<false><<<dim3(512 / 32, 2048 / 32), tb, 0, stream>>>(w2, 2048, 512, w2T, nullptr);

  k_gemm<0, true><<<dim3(64, 12), 256, 0, stream>>>(xh, xl, wqkvTh, wqkvTl, b_qkv,
                                                    nullptr, nullptr, qh, ql, kh, kl, vT,
                                                    8192, 1536, 512);
  k_attn<<<dim3(16, 32), 256, 0, stream>>>(qh, ql, kh, kl, vT, attn);
  k_ln<<<8192, 64, 0, stream>>>(x, attn, g1, be1, x1f, x1h);
  k_gemm<1, false><<<dim3(64, 16), 256, 0, stream>>>(x1h, nullptr, w1T, nullptr, b1,
                                                     nullptr, hbuf, nullptr, nullptr, nullptr, nullptr, nullptr,
                                                     8192, 2048, 512);
  k_gemm<2, false><<<dim3(64, 4), 256, 0, stream>>>(hbuf, nullptr, w2T, nullptr, b2,
                                                    ffb, nullptr, nullptr, nullptr, nullptr, nullptr, nullptr,
                                                    8192, 512, 2048);
  k_ln<<<8192, 64, 0, stream>>>(x1f, ffb, g2, be2, out, nullptr);
}

// Round 3
// 231.147 us; speedup vs baseline: 1.1908x; 1.1908x over previous
//
#include <hip/hip_runtime.h>

typedef _Float16 f16;
typedef _Float16 f16x4 __attribute__((ext_vector_type(4)));
typedef _Float16 f16x8 __attribute__((ext_vector_type(8)));
typedef float    f32x4 __attribute__((ext_vector_type(4)));

#define QK_SCALE 11.5416528f  // 8 * log2(e): scores pre-scaled into exp2 domain

__device__ __forceinline__ void g2l16(const void* g, void* l) {
  __builtin_amdgcn_global_load_lds(
      (__attribute__((address_space(1))) const unsigned int*)g,
      (__attribute__((address_space(3))) unsigned int*)l, 16, 0, 0);
}

__device__ __forceinline__ f32x4 mfma16(f16x8 a, f16x8 b, f32x4 c) {
  return __builtin_amdgcn_mfma_f32_16x16x32_f16(a, b, c, 0, 0, 0);
}

// XOR-swizzled LDS offsets (f16 units). Rows of 64 f16 (8x16B chunks) / 32 f16 (4x16B chunks).
__device__ __forceinline__ int swz64(int row, int c) { return row * 64 + ((c ^ (row & 7)) << 3); }
__device__ __forceinline__ int swz32(int row, int c) { return row * 32 + ((c ^ ((row >> 1) & 3)) << 3); }

// ---------------- fp32 -> fp16 hi/lo split (vectorized) ----------------
__global__ __launch_bounds__(256) void k_split(const float* __restrict__ in,
                                               f16* __restrict__ hi, f16* __restrict__ lo, int n4) {
  int i = blockIdx.x * 256 + threadIdx.x;
  if (i >= n4) return;
  f32x4 v = ((const f32x4*)in)[i];
  f16x4 h, l;
#pragma unroll
  for (int j = 0; j < 4; ++j) {
    f16 hv = (f16)v[j];
    h[j] = hv;
    l[j] = (f16)(v[j] - (float)hv);
  }
  ((f16x4*)hi)[i] = h;
  ((f16x4*)lo)[i] = l;
}

// ---------------- transpose fp32 [K][N] -> fp16 [N][K] (hi, optional lo) ----------------
template <bool WLO>
__global__ __launch_bounds__(256) void k_transpose_split(const float* __restrict__ in, int K, int N,
                                                         f16* __restrict__ oh, f16* __restrict__ ol) {
  __shared__ float t[32][33];
  const int tx = threadIdx.x, ty = threadIdx.y;
  const int n0 = blockIdx.x * 32, k0 = blockIdx.y * 32;
#pragma unroll
  for (int j = 0; j < 4; ++j)
    t[ty + j * 8][tx] = in[(size_t)(k0 + ty + j * 8) * N + n0 + tx];
  __syncthreads();
#pragma unroll
  for (int j = 0; j < 4; ++j) {
    float v = t[tx][ty + j * 8];
    f16 hv = (f16)v;
    size_t o = (size_t)(n0 + ty + j * 8) * K + k0 + tx;
    oh[o] = hv;
    if (WLO) ol[o] = (f16)(v - (float)hv);
  }
}

// ---------------- GEMM: C[M,N] = A[M,K] * B[K,N], B given transposed [N][K] ----------------
// EPI 0: qkv scatter (bias, split q(scaled)/k hi+lo per-head, vT fp16)
// EPI 1: relu -> fp16 out
// EPI 2: bias -> fp32 out
template <int EPI, bool SPLIT>
__global__ __launch_bounds__(256, 2) void k_gemm(
    const f16* __restrict__ Ah, const f16* __restrict__ Al,
    const f16* __restrict__ Bh, const f16* __restrict__ Bl,
    const float* __restrict__ bias,
    float* __restrict__ outF, f16* __restrict__ outH,
    f16* __restrict__ oqh, f16* __restrict__ oql,
    f16* __restrict__ okh, f16* __restrict__ okl, f16* __restrict__ ovT,
    int M, int N, int K) {
  constexpr int NB = SPLIT ? 2 : 1;
  __shared__ f16 As[NB][128 * 32];
  __shared__ f16 Bs[NB][128 * 32];

  const int tid = threadIdx.x;
  const int bm = blockIdx.x, bn = blockIdx.y;
  const int w = tid >> 6, lane = tid & 63;
  const int wr = w >> 1, wc = w & 1;
  const int lrow = lane & 15, lgrp = lane >> 4;

  f32x4 acc[4][4] = {};

  const int nkt = K >> 5;
  for (int kt = 0; kt < nkt; ++kt) {
    __syncthreads();
    const int kk = kt << 5;
#pragma unroll
    for (int c = 0; c < 2; ++c) {
      const int i = tid + (c << 8);
      const int row = i >> 2;
      const int gch = ((i & 3) ^ ((i >> 3) & 3)) << 3;  // swizzled source chunk
      const size_t aoff = (size_t)(bm * 128 + row) * K + kk + gch;
      const size_t boff = (size_t)(bn * 128 + row) * K + kk + gch;
      g2l16(Ah + aoff, &As[0][i * 8]);
      g2l16(Bh + boff, &Bs[0][i * 8]);
      if (SPLIT) {
        g2l16(Al + aoff, &As[1][i * 8]);
        g2l16(Bl + boff, &Bs[1][i * 8]);
      }
    }
    __syncthreads();

    f16x8 a0[4], a1[4], b0[4], b1[4];
#pragma unroll
    for (int mf = 0; mf < 4; ++mf) {
      const int off = swz32(wr * 64 + mf * 16 + lrow, lgrp);
      a0[mf] = *(const f16x8*)&As[0][off];
      if (SPLIT) a1[mf] = *(const f16x8*)&As[SPLIT ? 1 : 0][off];
    }
#pragma unroll
    for (int nf = 0; nf < 4; ++nf) {
      const int off = swz32(wc * 64 + nf * 16 + lrow, lgrp);
      b0[nf] = *(const f16x8*)&Bs[0][off];
      if (SPLIT) b1[nf] = *(const f16x8*)&Bs[SPLIT ? 1 : 0][off];
    }
#pragma unroll
    for (int mf = 0; mf < 4; ++mf)
#pragma unroll
      for (int nf = 0; nf < 4; ++nf) {
        acc[mf][nf] = mfma16(a0[mf], b0[nf], acc[mf][nf]);
        if (SPLIT) {
          acc[mf][nf] = mfma16(a0[mf], b1[nf], acc[mf][nf]);
          acc[mf][nf] = mfma16(a1[mf], b0[nf], acc[mf][nf]);
        }
      }
  }

  const int rowbase = bm * 128 + wr * 64 + lgrp * 4;
  const int colbase = bn * 128 + wc * 64 + lrow;
#pragma unroll
  for (int mf = 0; mf < 4; ++mf) {
#pragma unroll
    for (int nf = 0; nf < 4; ++nf) {
      const int gc = colbase + nf * 16;
      const float bv = bias[gc];
#pragma unroll
      for (int r = 0; r < 4; ++r) {
        const int gr = rowbase + mf * 16 + r;
        const float val = acc[mf][nf][r] + bv;
        if (EPI == 0) {
          const int bb = gr >> 11, tok = gr & 2047;
          const int kind = gc >> 9, hh = (gc >> 6) & 7, dd = gc & 63;
          const size_t bhp = (size_t)((bb << 3) + hh);
          const size_t qidx = (bhp * 2048 + tok) * 64 + dd;
          if (kind == 0) {
            const float sv = val * QK_SCALE;  // fold score scale + log2e into q
            const f16 hv = (f16)sv;
            oqh[qidx] = hv; oql[qidx] = (f16)(sv - (float)hv);
          } else if (kind == 1) {
            const f16 hv = (f16)val;
            okh[qidx] = hv; okl[qidx] = (f16)(val - (float)hv);
          } else {
            ovT[(bhp * 64 + dd) * 2048 + tok] = (f16)val;
          }
        } else if (EPI == 1) {
          outH[(size_t)gr * N + gc] = (f16)fmaxf(val, 0.f);
        } else {
          outF[(size_t)gr * N + gc] = val;
        }
      }
    }
  }
}

// ---------------- fused flash attention ----------------
// grid (32 qtiles of 64 rows, 32 bh); block 256 = 4 waves; wave handles 16 q-rows.
// Q (hi+lo, pre-scaled by 8*log2e) in registers (16 VGPRs); K/V in LDS (32 KB -> 4+ blocks/CU).
// S^T = mfma(K, Q) (split fp16, 3 mfma); online softmax in exp2 domain with defer-max;
// O^T = mfma(V^T, P^T).
__global__ __launch_bounds__(256, 3) void k_attn(
    const f16* __restrict__ Qh, const f16* __restrict__ Ql,
    const f16* __restrict__ Kh, const f16* __restrict__ Kl,
    const f16* __restrict__ Vt, float* __restrict__ out) {
  __shared__ f16 sKh[64 * 64], sKl[64 * 64], sVt[64 * 64];
  __shared__ f16 sPt[4][16 * 64];

  const int tid = threadIdx.x;
  const int qt = blockIdx.x, bh = blockIdx.y;
  const int w = tid >> 6, lane = tid & 63;
  const int lrow = lane & 15, lgrp = lane >> 4;

  // Q fragments (16 rows for this wave) straight from global into registers.
  const size_t qbase = (((size_t)bh * 2048) + qt * 64 + w * 16) * 64;
  f16x8 qh8[2], ql8[2];
#pragma unroll
  for (int ks = 0; ks < 2; ++ks) {
    const size_t o = qbase + (size_t)lrow * 64 + (ks * 4 + lgrp) * 8;
    qh8[ks] = *(const f16x8*)(Qh + o);
    ql8[ks] = *(const f16x8*)(Ql + o);
  }

  float m_run = -3e38f;
  float l_run = 0.f;
  f32x4 oacc[4] = {};

  for (int kt = 0; kt < 32; ++kt) {
    __syncthreads();
    {
      const size_t koff = ((size_t)bh * 2048 + (size_t)kt * 64) * 64;
#pragma unroll
      for (int c = 0; c < 2; ++c) {
        const int i = tid + (c << 8);
        const int row = i >> 3;
        const int gch = ((i & 7) ^ (row & 7)) << 3;
        g2l16(Kh + koff + row * 64 + gch, &sKh[i * 8]);
        g2l16(Kl + koff + row * 64 + gch, &sKl[i * 8]);
        g2l16(Vt + ((size_t)bh * 64 + row) * 2048 + (size_t)kt * 64 + gch, &sVt[i * 8]);
      }
    }
    __syncthreads();

    f32x4 sacc[4] = {};
#pragma unroll
    for (int ks = 0; ks < 2; ++ks) {
#pragma unroll
      for (int kf = 0; kf < 4; ++kf) {
        const int off = swz64(kf * 16 + lrow, ks * 4 + lgrp);
        const f16x8 kh8 = *(const f16x8*)&sKh[off];
        const f16x8 kl8 = *(const f16x8*)&sKl[off];
        sacc[kf] = mfma16(kh8, qh8[ks], sacc[kf]);
        sacc[kf] = mfma16(kh8, ql8[ks], sacc[kf]);
        sacc[kf] = mfma16(kl8, qh8[ks], sacc[kf]);
      }
    }

    // online softmax (exp2 domain; scores already scaled by 8*log2e)
    {
      float mt = sacc[0][0];
#pragma unroll
      for (int kf = 0; kf < 4; ++kf)
#pragma unroll
        for (int r = 0; r < 4; ++r) mt = fmaxf(mt, sacc[kf][r]);
      mt = fmaxf(mt, __shfl_xor(mt, 16, 64));
      mt = fmaxf(mt, __shfl_xor(mt, 32, 64));
      float mcur = m_run;
      // defer-max: only rescale when some row's tile max grew past m+8 (P bounded by 2^8)
      if (!__all(mt <= mcur + 8.0f)) {
        const float mnew = fmaxf(mcur, mt);
        const float corr = __builtin_amdgcn_exp2f(mcur - mnew);
        m_run = mnew;
        l_run *= corr;
#pragma unroll
        for (int hf = 0; hf < 4; ++hf) oacc[hf] = oacc[hf] * corr;
        mcur = mnew;
      }
      float ps = 0.f;
#pragma unroll
      for (int kf = 0; kf < 4; ++kf) {
        f16x4 pv;
#pragma unroll
        for (int r = 0; r < 4; ++r) {
          const float p = __builtin_amdgcn_exp2f(sacc[kf][r] - mcur);
          ps += p;
          pv[r] = (f16)p;
        }
        *(f16x4*)&sPt[w][swz64(lrow, kf * 2 + (lgrp >> 1)) + ((lgrp & 1) << 2)] = pv;
      }
      ps += __shfl_xor(ps, 16, 64);
      ps += __shfl_xor(ps, 32, 64);
      l_run += ps;
    }

#pragma unroll
    for (int ks = 0; ks < 2; ++ks) {
      const f16x8 pb = *(const f16x8*)&sPt[w][swz64(lrow, ks * 4 + lgrp)];
#pragma unroll
      for (int hf = 0; hf < 4; ++hf) {
        const f16x8 va = *(const f16x8*)&sVt[swz64(hf * 16 + lrow, ks * 4 + lgrp)];
        oacc[hf] = mfma16(va, pb, oacc[hf]);
      }
    }
  }

  const int b = bh >> 3, h = bh & 7;
  const float inv = 1.0f / l_run;
  const int t = b * 2048 + qt * 64 + w * 16 + lrow;
#pragma unroll
  for (int hf = 0; hf < 4; ++hf) {
    f32x4 o = oacc[hf] * inv;
    *(f32x4*)(out + (size_t)t * 512 + h * 64 + hf * 16 + lgrp * 4) = o;
  }
}

// ---------------- residual + layernorm (one wave per row of 512) ----------------
__global__ __launch_bounds__(64) void k_ln(const float* __restrict__ X, const float* __restrict__ R,
                                           const float* __restrict__ g, const float* __restrict__ be,
                                           float* __restrict__ outF, f16* __restrict__ outH) {
  const int row = blockIdx.x, t = threadIdx.x;
  const size_t base = (size_t)row * 512 + t * 8;
  f32x4 x0 = *(const f32x4*)(X + base);
  f32x4 x1 = *(const f32x4*)(X + base + 4);
  f32x4 r0 = *(const f32x4*)(R + base);
  f32x4 r1 = *(const f32x4*)(R + base + 4);
  x0 = x0 + r0;
  x1 = x1 + r1;
  float s = 0.f, ss = 0.f;
#pragma unroll
  for (int j = 0; j < 4; ++j) { s += x0[j] + x1[j]; ss += x0[j] * x0[j] + x1[j] * x1[j]; }
#pragma unroll
  for (int o = 32; o; o >>= 1) {
    s += __shfl_xor(s, o, 64);
    ss += __shfl_xor(ss, o, 64);
  }
  const float mean = s * (1.f / 512.f);
  const float var = ss * (1.f / 512.f) - mean * mean;
  const float rs = rsqrtf(var + 1e-5f);
  f32x4 g0 = *(const f32x4*)(g + t * 8);
  f32x4 g1v = *(const f32x4*)(g + t * 8 + 4);
  f32x4 b0 = *(const f32x4*)(be + t * 8);
  f32x4 b1 = *(const f32x4*)(be + t * 8 + 4);
  f32x4 y0 = (x0 - mean) * rs * g0 + b0;
  f32x4 y1 = (x1 - mean) * rs * g1v + b1;
  *(f32x4*)(outF + base) = y0;
  *(f32x4*)(outF + base + 4) = y1;
  if (outH != nullptr) {
    f16x8 hx;
#pragma unroll
    for (int j = 0; j < 4; ++j) { hx[j] = (f16)y0[j]; hx[j + 4] = (f16)y1[j]; }
    *(f16x8*)(outH + base) = hx;
  }
}

extern "C" void kernel_launch(void* const* d_in, const int* in_sizes, int n_in,
                              void* d_out, int out_size, void* d_ws, size_t ws_size,
                              hipStream_t stream) {
  (void)in_sizes; (void)n_in; (void)out_size;
  const float* x = (const float*)d_in[0];
  const float* w_qkv = (const float*)d_in[1];
  const float* b_qkv = (const float*)d_in[2];
  const float* w1 = (const float*)d_in[3];
  const float* b1 = (const float*)d_in[4];
  const float* w2 = (const float*)d_in[5];
  const float* b2 = (const float*)d_in[6];
  const float* g1 = (const float*)d_in[7];
  const float* be1 = (const float*)d_in[8];
  const float* g2 = (const float*)d_in[9];
  const float* be2 = (const float*)d_in[10];
  float* out = (float*)d_out;

  char* p = (char*)d_ws;
  auto take = [&](size_t bytes) {
    char* r = p;
    p += (bytes + 255) & ~(size_t)255;
    return r;
  };
  f16* xh = (f16*)take(8192ull * 512 * 2);
  f16* xl = (f16*)take(8192ull * 512 * 2);
  f16* wqkvTh = (f16*)take(1536ull * 512 * 2);
  f16* wqkvTl = (f16*)take(1536ull * 512 * 2);
  f16* w1T = (f16*)take(2048ull * 512 * 2);
  f16* w2T = (f16*)take(512ull * 2048 * 2);
  f16* qh = (f16*)take(32ull * 2048 * 64 * 2);
  f16* ql = (f16*)take(32ull * 2048 * 64 * 2);
  f16* kh = (f16*)take(32ull * 2048 * 64 * 2);
  f16* kl = (f16*)take(32ull * 2048 * 64 * 2);
  f16* vT = (f16*)take(32ull * 64 * 2048 * 2);
  float* attn = (float*)take(8192ull * 512 * 4);
  float* x1f = (float*)take(8192ull * 512 * 4);
  f16* x1h = (f16*)take(8192ull * 512 * 2);
  // reuse regions (stage lifetimes are disjoint):
  f16* hbuf = qh;        // [8192][2048] fp16 = 32MB fits in qh..kl (32MB)
  float* ffb = attn;     // [8192][512] fp32, attn consumed by LN1 before ff2

  if ((size_t)(p - (char*)d_ws) > ws_size) return;  // insufficient workspace -> loud validation fail

  dim3 tb(32, 8);
  k_split<<<4096, 256, 0, stream>>>(x, xh, xl, 8192 * 512 / 4);
  k_transpose_split<true><<<dim3(1536 / 32, 512 / 32), tb, 0, stream>>>(w_qkv, 512, 1536, wqkvTh, wqkvTl);
  k_transpose_split<false><<<dim3(2048 / 32, 512 / 32), tb, 0, stream>>>(w1, 512, 2048, w1T, nullptr);
  k_transpose_split<false><<<dim3(512 / 32, 2048 / 32), tb, 0, stream>>>(w2, 2048, 512, w2T, nullptr);

  k_gemm<0, true><<<dim3(64, 12), 256, 0, stream>>>(xh, xl, wqkvTh, wqkvTl, b_qkv,
                                                    nullptr, nullptr, qh, ql, kh, kl, vT,
                                                    8192, 1536, 512);
  k_attn<<<dim3(32, 32), 256, 0, stream>>>(qh, ql, kh, kl, vT, attn);
  k_ln<<<8192, 64, 0, stream>>>(x, attn, g1, be1, x1f, x1h);
  k_gemm<1, false><<<dim3(64, 16), 256, 0, stream>>>(x1h, nullptr, w1T, nullptr, b1,
                                                     nullptr, hbuf, nullptr, nullptr, nullptr, nullptr, nullptr,
                                                     8192, 2048, 512);
  k_gemm<2, false><<<dim3(64, 4), 256, 0, stream>>>(hbuf, nullptr, w2T, nullptr, b2,
                                                    ffb, nullptr, nullptr, nullptr, nullptr, nullptr, nullptr,
                                                    8192, 512, 2048);
  k_ln<<<8192, 64, 0, stream>>>(x1f, ffb, g2, be2, out, nullptr);
}

// Round 4
// 213.154 us; speedup vs baseline: 1.2913x; 1.0844x over previous
//
#include <hip/hip_runtime.h>

typedef _Float16 f16;
typedef _Float16 f16x4 __attribute__((ext_vector_type(4)));
typedef _Float16 f16x8 __attribute__((ext_vector_type(8)));
typedef float    f32x4 __attribute__((ext_vector_type(4)));

#define QK_SCALE 11.5416528f  // 8 * log2(e): scores pre-scaled into exp2 domain

__device__ __forceinline__ void g2l16(const void* g, void* l) {
  __builtin_amdgcn_global_load_lds(
      (__attribute__((address_space(1))) const unsigned int*)g,
      (__attribute__((address_space(3))) unsigned int*)l, 16, 0, 0);
}

__device__ __forceinline__ f32x4 mfma16(f16x8 a, f16x8 b, f32x4 c) {
  return __builtin_amdgcn_mfma_f32_16x16x32_f16(a, b, c, 0, 0, 0);
}

// XOR-swizzled LDS offsets (f16 units). Rows of 64 f16 (8x16B chunks) / 32 f16 (4x16B chunks).
__device__ __forceinline__ int swz64(int row, int c) { return row * 64 + ((c ^ (row & 7)) << 3); }
__device__ __forceinline__ int swz32(int row, int c) { return row * 32 + ((c ^ ((row >> 1) & 3)) << 3); }

// ---------------- fp32 -> fp16 hi/lo split (vectorized) ----------------
__global__ __launch_bounds__(256) void k_split(const float* __restrict__ in,
                                               f16* __restrict__ hi, f16* __restrict__ lo, int n4) {
  int i = blockIdx.x * 256 + threadIdx.x;
  if (i >= n4) return;
  f32x4 v = ((const f32x4*)in)[i];
  f16x4 h, l;
#pragma unroll
  for (int j = 0; j < 4; ++j) {
    f16 hv = (f16)v[j];
    h[j] = hv;
    l[j] = (f16)(v[j] - (float)hv);
  }
  ((f16x4*)hi)[i] = h;
  ((f16x4*)lo)[i] = l;
}

// ---------------- transpose fp32 [K][N] -> fp16 [N][K] (hi, optional lo) ----------------
template <bool WLO>
__global__ __launch_bounds__(256) void k_transpose_split(const float* __restrict__ in, int K, int N,
                                                         f16* __restrict__ oh, f16* __restrict__ ol) {
  __shared__ float t[32][33];
  const int tx = threadIdx.x, ty = threadIdx.y;
  const int n0 = blockIdx.x * 32, k0 = blockIdx.y * 32;
#pragma unroll
  for (int j = 0; j < 4; ++j)
    t[ty + j * 8][tx] = in[(size_t)(k0 + ty + j * 8) * N + n0 + tx];
  __syncthreads();
#pragma unroll
  for (int j = 0; j < 4; ++j) {
    float v = t[tx][ty + j * 8];
    f16 hv = (f16)v;
    size_t o = (size_t)(n0 + ty + j * 8) * K + k0 + tx;
    oh[o] = hv;
    if (WLO) ol[o] = (f16)(v - (float)hv);
  }
}

// ---------------- GEMM: C[M,N] = A[M,K] * B[K,N], B given transposed [N][K] ----------------
// EPI 0: qkv scatter (bias, split q(scaled) hi+lo, k hi, vT fp16)
// EPI 1: relu -> fp16 out
// EPI 2: bias -> fp32 out
template <int EPI, bool SPLIT>
__global__ __launch_bounds__(256, SPLIT ? 2 : 3) void k_gemm(
    const f16* __restrict__ Ah, const f16* __restrict__ Al,
    const f16* __restrict__ Bh, const f16* __restrict__ Bl,
    const float* __restrict__ bias,
    float* __restrict__ outF, f16* __restrict__ outH,
    f16* __restrict__ oqh, f16* __restrict__ oql,
    f16* __restrict__ okh, f16* __restrict__ ovT,
    int M, int N, int K) {
  constexpr int NB = SPLIT ? 2 : 1;
  __shared__ f16 As[NB][128 * 32];
  __shared__ f16 Bs[NB][128 * 32];

  const int tid = threadIdx.x;
  const int bm = blockIdx.x, bn = blockIdx.y;
  const int w = tid >> 6, lane = tid & 63;
  const int wr = w >> 1, wc = w & 1;
  const int lrow = lane & 15, lgrp = lane >> 4;

  f32x4 acc[4][4] = {};

  const int nkt = K >> 5;
  for (int kt = 0; kt < nkt; ++kt) {
    __syncthreads();
    const int kk = kt << 5;
#pragma unroll
    for (int c = 0; c < 2; ++c) {
      const int i = tid + (c << 8);
      const int row = i >> 2;
      const int gch = ((i & 3) ^ ((i >> 3) & 3)) << 3;  // swizzled source chunk
      const size_t aoff = (size_t)(bm * 128 + row) * K + kk + gch;
      const size_t boff = (size_t)(bn * 128 + row) * K + kk + gch;
      g2l16(Ah + aoff, &As[0][i * 8]);
      g2l16(Bh + boff, &Bs[0][i * 8]);
      if (SPLIT) {
        g2l16(Al + aoff, &As[1][i * 8]);
        g2l16(Bl + boff, &Bs[1][i * 8]);
      }
    }
    __syncthreads();

    f16x8 a0[4], a1[4], b0[4], b1[4];
#pragma unroll
    for (int mf = 0; mf < 4; ++mf) {
      const int off = swz32(wr * 64 + mf * 16 + lrow, lgrp);
      a0[mf] = *(const f16x8*)&As[0][off];
      if (SPLIT) a1[mf] = *(const f16x8*)&As[SPLIT ? 1 : 0][off];
    }
#pragma unroll
    for (int nf = 0; nf < 4; ++nf) {
      const int off = swz32(wc * 64 + nf * 16 + lrow, lgrp);
      b0[nf] = *(const f16x8*)&Bs[0][off];
      if (SPLIT) b1[nf] = *(const f16x8*)&Bs[SPLIT ? 1 : 0][off];
    }
#pragma unroll
    for (int mf = 0; mf < 4; ++mf)
#pragma unroll
      for (int nf = 0; nf < 4; ++nf) {
        acc[mf][nf] = mfma16(a0[mf], b0[nf], acc[mf][nf]);
        if (SPLIT) {
          acc[mf][nf] = mfma16(a0[mf], b1[nf], acc[mf][nf]);
          acc[mf][nf] = mfma16(a1[mf], b0[nf], acc[mf][nf]);
        }
      }
  }

  const int rowbase = bm * 128 + wr * 64 + lgrp * 4;
  const int colbase = bn * 128 + wc * 64 + lrow;
#pragma unroll
  for (int mf = 0; mf < 4; ++mf) {
#pragma unroll
    for (int nf = 0; nf < 4; ++nf) {
      const int gc = colbase + nf * 16;
      const float bv = bias[gc];
#pragma unroll
      for (int r = 0; r < 4; ++r) {
        const int gr = rowbase + mf * 16 + r;
        const float val = acc[mf][nf][r] + bv;
        if (EPI == 0) {
          const int bb = gr >> 11, tok = gr & 2047;
          const int kind = gc >> 9, hh = (gc >> 6) & 7, dd = gc & 63;
          const size_t bhp = (size_t)((bb << 3) + hh);
          const size_t qidx = (bhp * 2048 + tok) * 64 + dd;
          if (kind == 0) {
            const float sv = val * QK_SCALE;  // fold score scale + log2e into q
            const f16 hv = (f16)sv;
            oqh[qidx] = hv; oql[qidx] = (f16)(sv - (float)hv);
          } else if (kind == 1) {
            okh[qidx] = (f16)val;
          } else {
            ovT[(bhp * 64 + dd) * 2048 + tok] = (f16)val;
          }
        } else if (EPI == 1) {
          outH[(size_t)gr * N + gc] = (f16)fmaxf(val, 0.f);
        } else {
          outF[(size_t)gr * N + gc] = val;
        }
      }
    }
  }
}

// ---------------- fused flash attention ----------------
// grid (32 qtiles of 64 rows, 32 bh); block 256 = 4 waves; wave handles 16 q-rows.
// Q (hi+lo, pre-scaled by 8*log2e) in registers; K (fp16 hi only) + V double-buffered in LDS
// (40 KB); ONE barrier per K-tile: prefetch tile t+1 issued before compute of tile t.
// S^T = mfma(K, Q) 2-term split; online softmax in exp2 domain with defer-max; O^T = mfma(V^T, P^T).
__global__ __launch_bounds__(256, 3) void k_attn(
    const f16* __restrict__ Qh, const f16* __restrict__ Ql,
    const f16* __restrict__ Kh, const f16* __restrict__ Vt,
    float* __restrict__ out) {
  __shared__ f16 sKh[2][64 * 64], sVt[2][64 * 64];
  __shared__ f16 sPt[4][16 * 64];

  const int tid = threadIdx.x;
  const int qt = blockIdx.x, bh = blockIdx.y;
  const int w = tid >> 6, lane = tid & 63;
  const int lrow = lane & 15, lgrp = lane >> 4;

  // Q fragments (16 rows for this wave) straight from global into registers.
  const size_t qbase = (((size_t)bh * 2048) + qt * 64 + w * 16) * 64;
  f16x8 qh8[2], ql8[2];
#pragma unroll
  for (int ks = 0; ks < 2; ++ks) {
    const size_t o = qbase + (size_t)lrow * 64 + (ks * 4 + lgrp) * 8;
    qh8[ks] = *(const f16x8*)(Qh + o);
    ql8[ks] = *(const f16x8*)(Ql + o);
  }

  float m_run = -3e38f;
  float l_run = 0.f;
  f32x4 oacc[4] = {};

  auto stage = [&](int b, int kt) {
    const size_t koff = ((size_t)bh * 2048 + (size_t)kt * 64) * 64;
    const size_t voff = (size_t)bh * 64 * 2048 + (size_t)kt * 64;
#pragma unroll
    for (int c = 0; c < 2; ++c) {
      const int i = tid + (c << 8);
      const int row = i >> 3;
      const int gch = ((i & 7) ^ (row & 7)) << 3;
      g2l16(Kh + koff + (size_t)row * 64 + gch, &sKh[b][i * 8]);
      g2l16(Vt + voff + (size_t)row * 2048 + gch, &sVt[b][i * 8]);
    }
  };

  stage(0, 0);
  __syncthreads();

  for (int kt = 0; kt < 32; ++kt) {
    const int cur = kt & 1;
    if (kt < 31) stage(cur ^ 1, kt + 1);  // async prefetch; lands under compute

    f32x4 sacc[4] = {};
    __builtin_amdgcn_s_setprio(1);
#pragma unroll
    for (int ks = 0; ks < 2; ++ks) {
#pragma unroll
      for (int kf = 0; kf < 4; ++kf) {
        const int off = swz64(kf * 16 + lrow, ks * 4 + lgrp);
        const f16x8 kh8 = *(const f16x8*)&sKh[cur][off];
        sacc[kf] = mfma16(kh8, qh8[ks], sacc[kf]);
        sacc[kf] = mfma16(kh8, ql8[ks], sacc[kf]);
      }
    }
    __builtin_amdgcn_s_setprio(0);

    // online softmax (exp2 domain; scores already scaled by 8*log2e)
    {
      float mt = sacc[0][0];
#pragma unroll
      for (int kf = 0; kf < 4; ++kf)
#pragma unroll
        for (int r = 0; r < 4; ++r) mt = fmaxf(mt, sacc[kf][r]);
      mt = fmaxf(mt, __shfl_xor(mt, 16, 64));
      mt = fmaxf(mt, __shfl_xor(mt, 32, 64));
      float mcur = m_run;
      // defer-max: only rescale when some row's tile max grew past m+8 (P bounded by 2^8)
      if (!__all(mt <= mcur + 8.0f)) {
        const float mnew = fmaxf(mcur, mt);
        const float corr = __builtin_amdgcn_exp2f(mcur - mnew);
        m_run = mnew;
        l_run *= corr;
#pragma unroll
        for (int hf = 0; hf < 4; ++hf) oacc[hf] = oacc[hf] * corr;
        mcur = mnew;
      }
      float ps = 0.f;
#pragma unroll
      for (int kf = 0; kf < 4; ++kf) {
        f16x4 pv;
#pragma unroll
        for (int r = 0; r < 4; ++r) {
          const float p = __builtin_amdgcn_exp2f(sacc[kf][r] - mcur);
          ps += p;
          pv[r] = (f16)p;
        }
        *(f16x4*)&sPt[w][swz64(lrow, kf * 2 + (lgrp >> 1)) + ((lgrp & 1) << 2)] = pv;
      }
      ps += __shfl_xor(ps, 16, 64);
      ps += __shfl_xor(ps, 32, 64);
      l_run += ps;
    }

    __builtin_amdgcn_s_setprio(1);
#pragma unroll
    for (int ks = 0; ks < 2; ++ks) {
      const f16x8 pb = *(const f16x8*)&sPt[w][swz64(lrow, ks * 4 + lgrp)];
#pragma unroll
      for (int hf = 0; hf < 4; ++hf) {
        const f16x8 va = *(const f16x8*)&sVt[cur][swz64(hf * 16 + lrow, ks * 4 + lgrp)];
        oacc[hf] = mfma16(va, pb, oacc[hf]);
      }
    }
    __builtin_amdgcn_s_setprio(0);
    __syncthreads();  // drains this wave's prefetch (landed under compute) + releases buffers
  }

  const int b = bh >> 3, h = bh & 7;
  const float inv = 1.0f / l_run;
  const int t = b * 2048 + qt * 64 + w * 16 + lrow;
#pragma unroll
  for (int hf = 0; hf < 4; ++hf) {
    f32x4 o = oacc[hf] * inv;
    *(f32x4*)(out + (size_t)t * 512 + h * 64 + hf * 16 + lgrp * 4) = o;
  }
}

// ---------------- residual + layernorm (one wave per row of 512) ----------------
__global__ __launch_bounds__(64) void k_ln(const float* __restrict__ X, const float* __restrict__ R,
                                           const float* __restrict__ g, const float* __restrict__ be,
                                           float* __restrict__ outF, f16* __restrict__ outH) {
  const int row = blockIdx.x, t = threadIdx.x;
  const size_t base = (size_t)row * 512 + t * 8;
  f32x4 x0 = *(const f32x4*)(X + base);
  f32x4 x1 = *(const f32x4*)(X + base + 4);
  f32x4 r0 = *(const f32x4*)(R + base);
  f32x4 r1 = *(const f32x4*)(R + base + 4);
  x0 = x0 + r0;
  x1 = x1 + r1;
  float s = 0.f, ss = 0.f;
#pragma unroll
  for (int j = 0; j < 4; ++j) { s += x0[j] + x1[j]; ss += x0[j] * x0[j] + x1[j] * x1[j]; }
#pragma unroll
  for (int o = 32; o; o >>= 1) {
    s += __shfl_xor(s, o, 64);
    ss += __shfl_xor(ss, o, 64);
  }
  const float mean = s * (1.f / 512.f);
  const float var = ss * (1.f / 512.f) - mean * mean;
  const float rs = rsqrtf(var + 1e-5f);
  f32x4 g0 = *(const f32x4*)(g + t * 8);
  f32x4 g1v = *(const f32x4*)(g + t * 8 + 4);
  f32x4 b0 = *(const f32x4*)(be + t * 8);
  f32x4 b1 = *(const f32x4*)(be + t * 8 + 4);
  f32x4 y0 = (x0 - mean) * rs * g0 + b0;
  f32x4 y1 = (x1 - mean) * rs * g1v + b1;
  *(f32x4*)(outF + base) = y0;
  *(f32x4*)(outF + base + 4) = y1;
  if (outH != nullptr) {
    f16x8 hx;
#pragma unroll
    for (int j = 0; j < 4; ++j) { hx[j] = (f16)y0[j]; hx[j + 4] = (f16)y1[j]; }
    *(f16x8*)(outH + base) = hx;
  }
}

extern "C" void kernel_launch(void* const* d_in, const int* in_sizes, int n_in,
                              void* d_out, int out_size, void* d_ws, size_t ws_size,
                              hipStream_t stream) {
  (void)in_sizes; (void)n_in; (void)out_size;
  const float* x = (const float*)d_in[0];
  const float* w_qkv = (const float*)d_in[1];
  const float* b_qkv = (const float*)d_in[2];
  const float* w1 = (const float*)d_in[3];
  const float* b1 = (const float*)d_in[4];
  const float* w2 = (const float*)d_in[5];
  const float* b2 = (const float*)d_in[6];
  const float* g1 = (const float*)d_in[7];
  const float* be1 = (const float*)d_in[8];
  const float* g2 = (const float*)d_in[9];
  const float* be2 = (const float*)d_in[10];
  float* out = (float*)d_out;

  char* p = (char*)d_ws;
  auto take = [&](size_t bytes) {
    char* r = p;
    p += (bytes + 255) & ~(size_t)255;
    return r;
  };
  f16* xh = (f16*)take(8192ull * 512 * 2);
  f16* xl = (f16*)take(8192ull * 512 * 2);
  f16* wqkvTh = (f16*)take(1536ull * 512 * 2);
  f16* wqkvTl = (f16*)take(1536ull * 512 * 2);
  f16* w1T = (f16*)take(2048ull * 512 * 2);
  f16* w2T = (f16*)take(512ull * 2048 * 2);
  f16* qh = (f16*)take(32ull * 2048 * 64 * 2);
  f16* ql = (f16*)take(32ull * 2048 * 64 * 2);
  f16* kh = (f16*)take(32ull * 2048 * 64 * 2);
  f16* vT = (f16*)take(32ull * 64 * 2048 * 2);
  float* attn = (float*)take(8192ull * 512 * 4);
  float* x1f = (float*)take(8192ull * 512 * 4);
  f16* x1h = (f16*)take(8192ull * 512 * 2);
  // reuse regions (stage lifetimes are disjoint):
  f16* hbuf = qh;        // [8192][2048] fp16 = 32MB spans qh,ql,kh,vT (all dead after attn)
  float* ffb = attn;     // [8192][512] fp32, attn consumed by LN1 before ff2

  if ((size_t)(p - (char*)d_ws) > ws_size) return;  // insufficient workspace -> loud validation fail

  dim3 tb(32, 8);
  k_split<<<4096, 256, 0, stream>>>(x, xh, xl, 8192 * 512 / 4);
  k_transpose_split<true><<<dim3(1536 / 32, 512 / 32), tb, 0, stream>>>(w_qkv, 512, 1536, wqkvTh, wqkvTl);
  k_transpose_split<false><<<dim3(2048 / 32, 512 / 32), tb, 0, stream>>>(w1, 512, 2048, w1T, nullptr);
  k_transpose_split<false><<<dim3(512 / 32, 2048 / 32), tb, 0, stream>>>(w2, 2048, 512, w2T, nullptr);

  k_gemm<0, true><<<dim3(64, 12), 256, 0, stream>>>(xh, xl, wqkvTh, wqkvTl, b_qkv,
                                                    nullptr, nullptr, qh, ql, kh, vT,
                                                    8192, 1536, 512);
  k_attn<<<dim3(32, 32), 256, 0, stream>>>(qh, ql, kh, vT, attn);
  k_ln<<<8192, 64, 0, stream>>>(x, attn, g1, be1, x1f, x1h);
  k_gemm<1, false><<<dim3(64, 16), 256, 0, stream>>>(x1h, nullptr, w1T, nullptr, b1,
                                                     nullptr, hbuf, nullptr, nullptr, nullptr, nullptr,
                                                     8192, 2048, 512);
  k_gemm<2, false><<<dim3(64, 4), 256, 0, stream>>>(hbuf, nullptr, w2T, nullptr, b2,
                                                    ffb, nullptr, nullptr, nullptr, nullptr, nullptr,
                                                    8192, 512, 2048);
  k_ln<<<8192, 64, 0, stream>>>(x1f, ffb, g2, be2, out, nullptr);
}